// Round 10
// baseline (136.124 us; speedup 1.0000x reference)
//
#include <hip/hip_runtime.h>
#include <stdint.h>
#include <math.h>

#define CAND_CAP 8192
typedef unsigned long long ull;
typedef long long ll;
typedef unsigned int uint;
typedef float __attribute__((ext_vector_type(4))) f4;
typedef int __attribute__((ext_vector_type(4))) i4;

struct Ctrl {
  int sel0;     // selected top-8 bin
  int r0;       // remaining rank within top-8 bin
  int binsel;   // selected top-16 bin
  int r_in;     // remaining rank within top-16 bin
  int ncand;    // candidate count (atomic)
  int pad;
  ull Tpack;    // packed (key32<<32)|idx of threshold element
};

__device__ __forceinline__ uint fkey(float f) {
  uint u = __float_as_uint(f);
  return (u & 0x80000000u) ? ~u : (u | 0x80000000u);
}

// 4 edges/thread: int4 edge loads, 8 independent wm gathers (MLP), uint4 key write.
// Level-0 (top-8-bit) histogram LDS-aggregated, flushed as <=256 atomics/block.
__global__ void __launch_bounds__(256) k_keys(
    const int* __restrict__ ei, const float* __restrict__ wm,
    ll E, int D, uint* __restrict__ key32, uint* __restrict__ hist0) {
  __shared__ uint sh[256];
  int t = threadIdx.x;
  sh[t] = 0u;
  __syncthreads();
  int v = blockIdx.x * 256 + t;   // v indexes groups of 4 edges
  int4 s4 = ((const int4*)ei)[v];
  int4 d4 = ((const int4*)(ei + E))[v];
  float a0 = wm[(ll)s4.x * D + d4.x], b0 = wm[(ll)d4.x * D + s4.x];
  float a1 = wm[(ll)s4.y * D + d4.y], b1 = wm[(ll)d4.y * D + s4.y];
  float a2 = wm[(ll)s4.z * D + d4.z], b2 = wm[(ll)d4.z * D + s4.z];
  float a3 = wm[(ll)s4.w * D + d4.w], b3 = wm[(ll)d4.w * D + s4.w];
  uint4 k;
  k.x = fkey((float)((double)a0 + (double)b0));
  k.y = fkey((float)((double)a1 + (double)b1));
  k.z = fkey((float)((double)a2 + (double)b2));
  k.w = fkey((float)((double)a3 + (double)b3));
  ((uint4*)key32)[v] = k;
  atomicAdd(&sh[k.x >> 24], 1u);
  atomicAdd(&sh[k.y >> 24], 1u);
  atomicAdd(&sh[k.z >> 24], 1u);
  atomicAdd(&sh[k.w >> 24], 1u);
  __syncthreads();
  if (sh[t]) atomicAdd(&hist0[t], sh[t]);
}

// One block, 256 threads: scan 256 bins, pick bin containing rank r.
__global__ void k_pick0(const uint* __restrict__ hist0, int r, Ctrl* ctrl) {
  __shared__ uint sh[256];
  int t = threadIdx.x;
  uint c = hist0[t];
  sh[t] = c;
  __syncthreads();
  for (int off = 1; off < 256; off <<= 1) {
    uint v = sh[t];
    uint a = (t >= off) ? sh[t - off] : 0u;
    __syncthreads();
    sh[t] = v + a;
    __syncthreads();
  }
  uint incl = sh[t], excl = incl - c;
  if ((uint)r >= excl && (uint)r < incl) {  // exactly one thread
    ctrl->sel0 = t;
    ctrl->r0 = (int)((uint)r - excl);
  }
}

// Level-1: LDS hist of bits 16..23 among elements whose top-8 == sel0.
__global__ void __launch_bounds__(256) k_hist1(
    const uint* __restrict__ key32, const Ctrl* __restrict__ ctrl,
    uint* __restrict__ hist1) {
  __shared__ uint sh[256];
  int t = threadIdx.x;
  sh[t] = 0u;
  __syncthreads();
  uint sel0 = (uint)ctrl->sel0;
  uint4 k = ((const uint4*)key32)[blockIdx.x * 256 + t];
  if ((k.x >> 24) == sel0) atomicAdd(&sh[(k.x >> 16) & 0xFFu], 1u);
  if ((k.y >> 24) == sel0) atomicAdd(&sh[(k.y >> 16) & 0xFFu], 1u);
  if ((k.z >> 24) == sel0) atomicAdd(&sh[(k.z >> 16) & 0xFFu], 1u);
  if ((k.w >> 24) == sel0) atomicAdd(&sh[(k.w >> 16) & 0xFFu], 1u);
  __syncthreads();
  if (sh[t]) atomicAdd(&hist1[t], sh[t]);
}

__global__ void k_pick1(const uint* __restrict__ hist1, Ctrl* ctrl) {
  __shared__ uint sh[256];
  int t = threadIdx.x;
  uint c = hist1[t];
  sh[t] = c;
  __syncthreads();
  for (int off = 1; off < 256; off <<= 1) {
    uint v = sh[t];
    uint a = (t >= off) ? sh[t - off] : 0u;
    __syncthreads();
    sh[t] = v + a;
    __syncthreads();
  }
  uint incl = sh[t], excl = incl - c;
  uint r = (uint)ctrl->r0;
  if (r >= excl && r < incl) {  // exactly one thread
    ctrl->binsel = (ctrl->sel0 << 8) | t;
    ctrl->r_in = (int)(r - excl);
  }
}

// Collect candidates whose top-16 bits match binsel (~500 expected).
__global__ void k_cand(const uint* __restrict__ key32, int N, Ctrl* ctrl,
                       ull* __restrict__ cand) {
  int e = blockIdx.x * blockDim.x + threadIdx.x;
  if (e >= N) return;
  uint k = key32[e];
  if ((int)(k >> 16) == ctrl->binsel) {
    int p = atomicAdd(&ctrl->ncand, 1);
    if (p < CAND_CAP) cand[p] = ((ull)k << 32) | (uint)e;
  }
}

// Rank candidates by packed (key,idx); threshold = rank r_in element.
__global__ void k_pickT(const ull* __restrict__ cand, Ctrl* ctrl) {
  int nc = ctrl->ncand;
  if (nc > CAND_CAP) nc = CAND_CAP;
  int r = ctrl->r_in;
  for (int o = threadIdx.x; o < nc; o += blockDim.x) {
    ull my = cand[o];
    int cnt = 0;
    for (int i = 0; i < nc; ++i) cnt += (cand[i] < my) ? 1 : 0;
    if (cnt == r) ctrl->Tpack = my;   // exactly one (packs are unique)
  }
}

__device__ __forceinline__ int keptf(uint k, int e, ull T) {
  return ((((ull)k << 32) | (uint)e) > T) ? 1 : 0;
}

// Once-only: per-thread packed (excl-pos<<4)|flags, per-chunk sums, mask output.
__global__ void __launch_bounds__(256) k_scanA(
    const uint* __restrict__ key32, const Ctrl* __restrict__ ctrl,
    int* __restrict__ pw, int* __restrict__ bs, float* __restrict__ mask_out) {
  __shared__ int sh[256];
  int t = threadIdx.x, blk = blockIdx.x;
  ull T = ctrl->Tpack;
  uint4 k4 = ((const uint4*)key32)[blk * 256 + t];
  int e0 = blk * 1024 + t * 4;
  int f0 = keptf(k4.x, e0, T), f1 = keptf(k4.y, e0 + 1, T);
  int f2 = keptf(k4.z, e0 + 2, T), f3 = keptf(k4.w, e0 + 3, T);
  int c = f0 + f1 + f2 + f3;
  sh[t] = c;
  __syncthreads();
  for (int off = 1; off < 256; off <<= 1) {
    int v = sh[t];
    int a = (t >= off) ? sh[t - off] : 0;
    __syncthreads();
    sh[t] = v + a;
    __syncthreads();
  }
  int excl = sh[t] - c;
  pw[blk * 256 + t] = (excl << 4) | f0 | (f1 << 1) | (f2 << 2) | (f3 << 3);
  ((float4*)mask_out)[blk * 256 + t] =
      make_float4((float)f0, (float)f1, (float)f2, (float)f3);
  if (t == 255) bs[blk] = sh[255];
}

// Parallel exclusive scan of <=256 chunk counts.
__global__ void k_scanB(int* bs, int nb) {
  __shared__ int sh[256];
  int t = threadIdx.x;
  int v = (t < nb) ? bs[t] : 0;
  sh[t] = v;
  __syncthreads();
  for (int off = 1; off < 256; off <<= 1) {
    int x = sh[t];
    int a = (t >= off) ? sh[t - off] : 0;
    __syncthreads();
    sh[t] = x + a;
    __syncthreads();
  }
  if (t < nb) bs[t] = sh[t] - v;
}

// Batch-looped wave-autonomous compaction with 2-DEEP register prefetch:
// loads for batch b+2 issue ~2 iterations (~600-1000 cyc) before their use,
// covering HBM latency. Setup (pw/shfl/bs) amortized over BPG batches.
// No barriers (same-wave LDS program order). grid = (chunk, batch_group).
__global__ void __launch_bounds__(256) k_compact(
    const int* __restrict__ pw, const int* __restrict__ bs,
    const int* __restrict__ ei, const float* __restrict__ attr,
    ll E, int N, int Kkeep, ll BK, int BPG, float* __restrict__ out) {
  __shared__ float lds[4][3][264];   // [wave][row][slot], 16B-aligned rows
  int t = threadIdx.x;
  int w = t >> 6;       // wave id
  int l = t & 63;       // lane
  int blk = blockIdx.x;
  int b0 = blockIdx.y * BPG;
  int q = blk * 256 + t;            // pw slot; elems 4q..4q+3
  int wv = pw[q];
  int flags = wv & 15;
  int excl = wv >> 4;               // kept-count before elem 4q within 1024-chunk
  int subbase = __shfl(excl, 0);    // wave's sub-chunk base within chunk
  int wlast = __shfl(wv, 63);
  int cnt = (wlast >> 4) + __popc(wlast & 15) - subbase;   // kept in sub-chunk
  int poff = excl - subbase;        // position within wave's compacted run
  ll obase = (ll)bs[blk] + subbase; // batch-independent part of output offset
  float* L0 = lds[w][0];
  float* L1 = lds[w][1];
  float* L2 = lds[w][2];

  // prologue: load batches b0 and b0+1 (BPG >= 2)
  ll cb = (ll)b0 * N;
  i4 d0 = __builtin_nontemporal_load((const i4*)(ei + cb) + q);
  i4 d1 = __builtin_nontemporal_load((const i4*)(ei + E + cb) + q);
  f4 d2 = __builtin_nontemporal_load((const f4*)(attr + cb) + q);
  ll cb1 = (ll)(b0 + 1) * N;
  i4 e0 = __builtin_nontemporal_load((const i4*)(ei + cb1) + q);
  i4 e1 = __builtin_nontemporal_load((const i4*)(ei + E + cb1) + q);
  f4 e2 = __builtin_nontemporal_load((const f4*)(attr + cb1) + q);

  for (int bi = 0; bi < BPG; ++bi) {
    int b = b0 + bi;
    ll ob = (ll)b * Kkeep + obase;
    int al = (int)(ob & 3);
    int p = poff + al;              // stage shifted to output 16B phase
    if (flags & 1) { L0[p] = (float)d0.x; L1[p] = (float)d1.x; L2[p] = d2.x; p++; }
    if (flags & 2) { L0[p] = (float)d0.y; L1[p] = (float)d1.y; L2[p] = d2.y; p++; }
    if (flags & 4) { L0[p] = (float)d0.z; L1[p] = (float)d1.z; L2[p] = d2.z; p++; }
    if (flags & 8) { L0[p] = (float)d0.w; L1[p] = (float)d1.w; L2[p] = d2.w; }
    // issue batch b+2's loads (2-deep; hide HBM latency under 2 drains)
    i4 n0, n1; f4 n2;
    if (bi + 2 < BPG) {
      ll cb2 = (ll)(b + 2) * N;
      n0 = __builtin_nontemporal_load((const i4*)(ei + cb2) + q);
      n1 = __builtin_nontemporal_load((const i4*)(ei + E + cb2) + q);
      n2 = __builtin_nontemporal_load((const f4*)(attr + cb2) + q);
    }
    // drain (same-wave LDS program order; no barrier needed)
    int lo = al, hi = al + cnt;     // valid LDS index range (wave-uniform)
    int nslot = (hi + 3) >> 2;
    ll gbase = ob - al;             // 16B-aligned global base
    #pragma unroll
    for (int r = 0; r < 3; ++r) {
      const float* src = lds[w][r];
      float* dst = out + (ll)r * BK + gbase;
      for (int i = l; i < nslot; i += 64) {
        int j0 = 4 * i;
        f4 v = *(const f4*)(src + j0);
        if (j0 >= lo && j0 + 3 < hi) {
          __builtin_nontemporal_store(v, (f4*)(dst + j0));
        } else {
          if (j0 >= lo && j0 < hi)         __builtin_nontemporal_store(v.x, dst + j0);
          if (j0 + 1 >= lo && j0 + 1 < hi) __builtin_nontemporal_store(v.y, dst + j0 + 1);
          if (j0 + 2 >= lo && j0 + 2 < hi) __builtin_nontemporal_store(v.z, dst + j0 + 2);
          if (j0 + 3 >= lo && j0 + 3 < hi) __builtin_nontemporal_store(v.w, dst + j0 + 3);
        }
      }
    }
    d0 = e0; d1 = e1; d2 = e2;      // shift pipeline
    e0 = n0; e1 = n1; e2 = n2;
  }
}

extern "C" void kernel_launch(void* const* d_in, const int* in_sizes, int n_in,
                              void* d_out, int out_size, void* d_ws, size_t ws_size,
                              hipStream_t stream) {
  const int* ei = (const int*)d_in[0];
  const float* attr = (const float*)d_in[1];
  const float* wm = (const float*)d_in[3];

  int B = in_sizes[2] - 1;                          // 64
  ll E = (ll)in_sizes[0] / 2;                       // 16777216
  int e_per = (int)(E / B);                         // 262144
  int D = (int)llround(sqrt((double)in_sizes[3]));  // 4096
  int num_rm = (int)((double)e_per * 0.3);          // 78643
  int Kkeep = e_per - num_rm;                       // 183501
  ll BK = (ll)B * Kkeep;
  int nb = (e_per + 1023) / 1024;                   // 256

  char* w = (char*)d_ws;
  size_t off = 0;
  uint* key32 = (uint*)(w + off);  off += (size_t)e_per * 4;
  uint* hist0 = (uint*)(w + off);  off += 256 * 4;
  uint* hist1 = (uint*)(w + off);  off += 256 * 4;
  Ctrl* ctrl = (Ctrl*)(w + off);   off += 64;
  ull* cand = (ull*)(w + off);     off += (size_t)CAND_CAP * 8;
  int* bs = (int*)(w + off);       off += 1024;
  int* pw = (int*)(w + off);       off += (size_t)(e_per / 4) * 4;
  (void)ws_size; (void)n_in; (void)out_size;

  float* out = (float*)d_out;
  float* mask_out = out + 3 * BK;

  int BPG = 8;
  hipMemsetAsync(hist0, 0, 256 * 4 + 256 * 4 + 64, stream);
  k_keys<<<dim3(e_per / 1024), dim3(256), 0, stream>>>(ei, wm, E, D, key32, hist0);
  k_pick0<<<dim3(1), dim3(256), 0, stream>>>(hist0, num_rm - 1, ctrl);
  k_hist1<<<dim3(e_per / 1024), dim3(256), 0, stream>>>(key32, ctrl, hist1);
  k_pick1<<<dim3(1), dim3(256), 0, stream>>>(hist1, ctrl);
  k_cand<<<dim3(nb), dim3(1024), 0, stream>>>(key32, e_per, ctrl, cand);
  k_pickT<<<dim3(1), dim3(1024), 0, stream>>>(cand, ctrl);
  k_scanA<<<dim3(nb), dim3(256), 0, stream>>>(key32, ctrl, pw, bs, mask_out);
  k_scanB<<<dim3(1), dim3(256), 0, stream>>>(bs, nb);
  k_compact<<<dim3(nb, B / BPG), dim3(256), 0, stream>>>(pw, bs, ei, attr,
                                                         E, e_per, Kkeep, BK, BPG, out);
}

// Round 11
// 111.960 us; speedup vs baseline: 1.2158x; 1.2158x over previous
//
#include <hip/hip_runtime.h>
#include <stdint.h>
#include <math.h>

#define CAND_CAP 8192
typedef unsigned long long ull;
typedef long long ll;
typedef unsigned int uint;
typedef float __attribute__((ext_vector_type(4))) f4;
typedef int __attribute__((ext_vector_type(4))) i4;

struct Ctrl {
  int sel0;     // selected top-8 bin
  int r0;       // remaining rank within top-8 bin
  int binsel;   // selected top-16 bin
  int r_in;     // remaining rank within top-16 bin
  int ncand;    // candidate count (atomic)
  int pad;
  ull Tpack;    // packed (key32<<32)|idx of threshold element
};

__device__ __forceinline__ uint fkey(float f) {
  uint u = __float_as_uint(f);
  return (u & 0x80000000u) ? ~u : (u | 0x80000000u);
}

// 4 edges/thread: int4 edge loads, 8 independent wm gathers (MLP), uint4 key write.
// Level-0 (top-8-bit) histogram LDS-aggregated, flushed as <=256 atomics/block.
__global__ void __launch_bounds__(256) k_keys(
    const int* __restrict__ ei, const float* __restrict__ wm,
    ll E, int D, uint* __restrict__ key32, uint* __restrict__ hist0) {
  __shared__ uint sh[256];
  int t = threadIdx.x;
  sh[t] = 0u;
  __syncthreads();
  int v = blockIdx.x * 256 + t;   // v indexes groups of 4 edges
  int4 s4 = ((const int4*)ei)[v];
  int4 d4 = ((const int4*)(ei + E))[v];
  float a0 = wm[(ll)s4.x * D + d4.x], b0 = wm[(ll)d4.x * D + s4.x];
  float a1 = wm[(ll)s4.y * D + d4.y], b1 = wm[(ll)d4.y * D + s4.y];
  float a2 = wm[(ll)s4.z * D + d4.z], b2 = wm[(ll)d4.z * D + s4.z];
  float a3 = wm[(ll)s4.w * D + d4.w], b3 = wm[(ll)d4.w * D + s4.w];
  uint4 k;
  k.x = fkey((float)((double)a0 + (double)b0));
  k.y = fkey((float)((double)a1 + (double)b1));
  k.z = fkey((float)((double)a2 + (double)b2));
  k.w = fkey((float)((double)a3 + (double)b3));
  ((uint4*)key32)[v] = k;
  atomicAdd(&sh[k.x >> 24], 1u);
  atomicAdd(&sh[k.y >> 24], 1u);
  atomicAdd(&sh[k.z >> 24], 1u);
  atomicAdd(&sh[k.w >> 24], 1u);
  __syncthreads();
  if (sh[t]) atomicAdd(&hist0[t], sh[t]);
}

// One block, 256 threads: scan 256 bins, pick bin containing rank r.
__global__ void k_pick0(const uint* __restrict__ hist0, int r, Ctrl* ctrl) {
  __shared__ uint sh[256];
  int t = threadIdx.x;
  uint c = hist0[t];
  sh[t] = c;
  __syncthreads();
  for (int off = 1; off < 256; off <<= 1) {
    uint v = sh[t];
    uint a = (t >= off) ? sh[t - off] : 0u;
    __syncthreads();
    sh[t] = v + a;
    __syncthreads();
  }
  uint incl = sh[t], excl = incl - c;
  if ((uint)r >= excl && (uint)r < incl) {  // exactly one thread
    ctrl->sel0 = t;
    ctrl->r0 = (int)((uint)r - excl);
  }
}

// Level-1: LDS hist of bits 16..23 among elements whose top-8 == sel0.
__global__ void __launch_bounds__(256) k_hist1(
    const uint* __restrict__ key32, const Ctrl* __restrict__ ctrl,
    uint* __restrict__ hist1) {
  __shared__ uint sh[256];
  int t = threadIdx.x;
  sh[t] = 0u;
  __syncthreads();
  uint sel0 = (uint)ctrl->sel0;
  uint4 k = ((const uint4*)key32)[blockIdx.x * 256 + t];
  if ((k.x >> 24) == sel0) atomicAdd(&sh[(k.x >> 16) & 0xFFu], 1u);
  if ((k.y >> 24) == sel0) atomicAdd(&sh[(k.y >> 16) & 0xFFu], 1u);
  if ((k.z >> 24) == sel0) atomicAdd(&sh[(k.z >> 16) & 0xFFu], 1u);
  if ((k.w >> 24) == sel0) atomicAdd(&sh[(k.w >> 16) & 0xFFu], 1u);
  __syncthreads();
  if (sh[t]) atomicAdd(&hist1[t], sh[t]);
}

__global__ void k_pick1(const uint* __restrict__ hist1, Ctrl* ctrl) {
  __shared__ uint sh[256];
  int t = threadIdx.x;
  uint c = hist1[t];
  sh[t] = c;
  __syncthreads();
  for (int off = 1; off < 256; off <<= 1) {
    uint v = sh[t];
    uint a = (t >= off) ? sh[t - off] : 0u;
    __syncthreads();
    sh[t] = v + a;
    __syncthreads();
  }
  uint incl = sh[t], excl = incl - c;
  uint r = (uint)ctrl->r0;
  if (r >= excl && r < incl) {  // exactly one thread
    ctrl->binsel = (ctrl->sel0 << 8) | t;
    ctrl->r_in = (int)(r - excl);
  }
}

// Collect candidates whose top-16 bits match binsel (~500 expected).
__global__ void k_cand(const uint* __restrict__ key32, int N, Ctrl* ctrl,
                       ull* __restrict__ cand) {
  int e = blockIdx.x * blockDim.x + threadIdx.x;
  if (e >= N) return;
  uint k = key32[e];
  if ((int)(k >> 16) == ctrl->binsel) {
    int p = atomicAdd(&ctrl->ncand, 1);
    if (p < CAND_CAP) cand[p] = ((ull)k << 32) | (uint)e;
  }
}

// Rank candidates by packed (key,idx); threshold = rank r_in element.
__global__ void k_pickT(const ull* __restrict__ cand, Ctrl* ctrl) {
  int nc = ctrl->ncand;
  if (nc > CAND_CAP) nc = CAND_CAP;
  int r = ctrl->r_in;
  for (int o = threadIdx.x; o < nc; o += blockDim.x) {
    ull my = cand[o];
    int cnt = 0;
    for (int i = 0; i < nc; ++i) cnt += (cand[i] < my) ? 1 : 0;
    if (cnt == r) ctrl->Tpack = my;   // exactly one (packs are unique)
  }
}

__device__ __forceinline__ int keptf(uint k, int e, ull T) {
  return ((((ull)k << 32) | (uint)e) > T) ? 1 : 0;
}

// Once-only: per-thread packed (excl-pos<<4)|flags, per-chunk sums, mask output.
__global__ void __launch_bounds__(256) k_scanA(
    const uint* __restrict__ key32, const Ctrl* __restrict__ ctrl,
    int* __restrict__ pw, int* __restrict__ bs, float* __restrict__ mask_out) {
  __shared__ int sh[256];
  int t = threadIdx.x, blk = blockIdx.x;
  ull T = ctrl->Tpack;
  uint4 k4 = ((const uint4*)key32)[blk * 256 + t];
  int e0 = blk * 1024 + t * 4;
  int f0 = keptf(k4.x, e0, T), f1 = keptf(k4.y, e0 + 1, T);
  int f2 = keptf(k4.z, e0 + 2, T), f3 = keptf(k4.w, e0 + 3, T);
  int c = f0 + f1 + f2 + f3;
  sh[t] = c;
  __syncthreads();
  for (int off = 1; off < 256; off <<= 1) {
    int v = sh[t];
    int a = (t >= off) ? sh[t - off] : 0;
    __syncthreads();
    sh[t] = v + a;
    __syncthreads();
  }
  int excl = sh[t] - c;
  pw[blk * 256 + t] = (excl << 4) | f0 | (f1 << 1) | (f2 << 2) | (f3 << 3);
  ((float4*)mask_out)[blk * 256 + t] =
      make_float4((float)f0, (float)f1, (float)f2, (float)f3);
  if (t == 255) bs[blk] = sh[255];
}

// Parallel exclusive scan of <=256 chunk counts.
__global__ void k_scanB(int* bs, int nb) {
  __shared__ int sh[256];
  int t = threadIdx.x;
  int v = (t < nb) ? bs[t] : 0;
  sh[t] = v;
  __syncthreads();
  for (int off = 1; off < 256; off <<= 1) {
    int x = sh[t];
    int a = (t >= off) ? sh[t - off] : 0;
    __syncthreads();
    sh[t] = x + a;
    __syncthreads();
  }
  if (t < nb) bs[t] = sh[t] - v;
}

// Batch-looped wave-autonomous compaction. Each block owns one 1024-chunk and
// iterates 8 batches, reusing pw/shfl/bs setup; 1-deep register pipeline hides
// the next batch's loads under the current batch's LDS drain. No barriers.
// grid = (chunk, batch_group).
__global__ void __launch_bounds__(256) k_compact(
    const int* __restrict__ pw, const int* __restrict__ bs,
    const int* __restrict__ ei, const float* __restrict__ attr,
    ll E, int N, int Kkeep, ll BK, int BPG, float* __restrict__ out) {
  __shared__ float lds[4][3][264];   // [wave][row][slot], 16B-aligned rows
  int t = threadIdx.x;
  int w = t >> 6;       // wave id
  int l = t & 63;       // lane
  int blk = blockIdx.x;
  int b0 = blockIdx.y * BPG;
  int q = blk * 256 + t;            // pw slot; elems 4q..4q+3
  int wv = pw[q];
  int flags = wv & 15;
  int excl = wv >> 4;               // kept-count before elem 4q within 1024-chunk
  int subbase = __shfl(excl, 0);    // wave's sub-chunk base within chunk
  int wlast = __shfl(wv, 63);
  int cnt = (wlast >> 4) + __popc(wlast & 15) - subbase;   // kept in sub-chunk
  int poff = excl - subbase;        // position within wave's compacted run
  ll obase = (ll)bs[blk] + subbase; // batch-independent part of output offset
  float* L0 = lds[w][0];
  float* L1 = lds[w][1];
  float* L2 = lds[w][2];

  // prologue: load batch b0
  ll cb = (ll)b0 * N;
  i4 d0 = *((const i4*)(ei + cb) + q);
  i4 d1 = *((const i4*)(ei + E + cb) + q);
  f4 d2 = *((const f4*)(attr + cb) + q);

  for (int bi = 0; bi < BPG; ++bi) {
    int b = b0 + bi;
    ll ob = (ll)b * Kkeep + obase;
    int al = (int)(ob & 3);
    int p = poff + al;              // stage shifted to output 16B phase
    if (flags & 1) { L0[p] = (float)d0.x; L1[p] = (float)d1.x; L2[p] = d2.x; p++; }
    if (flags & 2) { L0[p] = (float)d0.y; L1[p] = (float)d1.y; L2[p] = d2.y; p++; }
    if (flags & 4) { L0[p] = (float)d0.z; L1[p] = (float)d1.z; L2[p] = d2.z; p++; }
    if (flags & 8) { L0[p] = (float)d0.w; L1[p] = (float)d1.w; L2[p] = d2.w; }
    // issue next batch's loads (independent; hide under drain)
    i4 n0, n1; f4 n2;
    if (bi + 1 < BPG) {
      ll cb2 = (ll)(b + 1) * N;
      n0 = *((const i4*)(ei + cb2) + q);
      n1 = *((const i4*)(ei + E + cb2) + q);
      n2 = *((const f4*)(attr + cb2) + q);
    }
    // drain (same-wave LDS program order; no barrier needed)
    int lo = al, hi = al + cnt;     // valid LDS index range (wave-uniform)
    int nslot = (hi + 3) >> 2;
    ll gbase = ob - al;             // 16B-aligned global base
    #pragma unroll
    for (int r = 0; r < 3; ++r) {
      const float* src = lds[w][r];
      float* dst = out + (ll)r * BK + gbase;
      for (int i = l; i < nslot; i += 64) {
        int j0 = 4 * i;
        f4 v = *(const f4*)(src + j0);
        if (j0 >= lo && j0 + 3 < hi) {
          __builtin_nontemporal_store(v, (f4*)(dst + j0));
        } else {
          if (j0 >= lo && j0 < hi)         __builtin_nontemporal_store(v.x, dst + j0);
          if (j0 + 1 >= lo && j0 + 1 < hi) __builtin_nontemporal_store(v.y, dst + j0 + 1);
          if (j0 + 2 >= lo && j0 + 2 < hi) __builtin_nontemporal_store(v.z, dst + j0 + 2);
          if (j0 + 3 >= lo && j0 + 3 < hi) __builtin_nontemporal_store(v.w, dst + j0 + 3);
        }
      }
    }
    d0 = n0; d1 = n1; d2 = n2;
  }
}

extern "C" void kernel_launch(void* const* d_in, const int* in_sizes, int n_in,
                              void* d_out, int out_size, void* d_ws, size_t ws_size,
                              hipStream_t stream) {
  const int* ei = (const int*)d_in[0];
  const float* attr = (const float*)d_in[1];
  const float* wm = (const float*)d_in[3];

  int B = in_sizes[2] - 1;                          // 64
  ll E = (ll)in_sizes[0] / 2;                       // 16777216
  int e_per = (int)(E / B);                         // 262144
  int D = (int)llround(sqrt((double)in_sizes[3]));  // 4096
  int num_rm = (int)((double)e_per * 0.3);          // 78643
  int Kkeep = e_per - num_rm;                       // 183501
  ll BK = (ll)B * Kkeep;
  int nb = (e_per + 1023) / 1024;                   // 256

  char* w = (char*)d_ws;
  size_t off = 0;
  uint* key32 = (uint*)(w + off);  off += (size_t)e_per * 4;
  uint* hist0 = (uint*)(w + off);  off += 256 * 4;
  uint* hist1 = (uint*)(w + off);  off += 256 * 4;
  Ctrl* ctrl = (Ctrl*)(w + off);   off += 64;
  ull* cand = (ull*)(w + off);     off += (size_t)CAND_CAP * 8;
  int* bs = (int*)(w + off);       off += 1024;
  int* pw = (int*)(w + off);       off += (size_t)(e_per / 4) * 4;
  (void)ws_size; (void)n_in; (void)out_size;

  float* out = (float*)d_out;
  float* mask_out = out + 3 * BK;

  int BPG = 8;
  hipMemsetAsync(hist0, 0, 256 * 4 + 256 * 4 + 64, stream);
  k_keys<<<dim3(e_per / 1024), dim3(256), 0, stream>>>(ei, wm, E, D, key32, hist0);
  k_pick0<<<dim3(1), dim3(256), 0, stream>>>(hist0, num_rm - 1, ctrl);
  k_hist1<<<dim3(e_per / 1024), dim3(256), 0, stream>>>(key32, ctrl, hist1);
  k_pick1<<<dim3(1), dim3(256), 0, stream>>>(hist1, ctrl);
  k_cand<<<dim3(nb), dim3(1024), 0, stream>>>(key32, e_per, ctrl, cand);
  k_pickT<<<dim3(1), dim3(1024), 0, stream>>>(cand, ctrl);
  k_scanA<<<dim3(nb), dim3(256), 0, stream>>>(key32, ctrl, pw, bs, mask_out);
  k_scanB<<<dim3(1), dim3(256), 0, stream>>>(bs, nb);
  k_compact<<<dim3(nb, B / BPG), dim3(256), 0, stream>>>(pw, bs, ei, attr,
                                                         E, e_per, Kkeep, BK, BPG, out);
}